// Round 1
// baseline (532.549 us; speedup 1.0000x reference)
//
#include <hip/hip_runtime.h>
#include <hip/hip_bf16.h>
#include <stdint.h>

// ---------------------------------------------------------------------------
// RoPE attention (B=2, SQ=4096, SK=16448, H=1, D=256) for MI355X (gfx950).
// Pipeline: rope-table -> mask detect/convert -> Q/K/V projections (+rope,
// bf16 cast, swizzled layouts) -> flash attention (MFMA 16x16x32 bf16,
// KV-split online softmax) -> split-K combine -> output GEMM (fp32).
// ---------------------------------------------------------------------------

typedef __attribute__((ext_vector_type(8))) short short8;   // 8 x bf16 bits
typedef __attribute__((ext_vector_type(4))) float f4;       // MFMA C/D frag

__device__ __forceinline__ unsigned short f2bf(float x) {
  union { float f; uint32_t u; } v; v.f = x;
  return (unsigned short)((v.u + 0x7FFFu + ((v.u >> 16) & 1u)) >> 16);  // RNE
}

__device__ __forceinline__ void gl_lds16(const void* g, void* l) {
  // async global->LDS, 16B per lane; LDS dest is wave-uniform base + lane*16
  __builtin_amdgcn_global_load_lds(
      (const __attribute__((address_space(1))) void*)g,
      (__attribute__((address_space(3))) void*)l, 16, 0, 0);
}

// ---- rope cos/sin table: [4096 pos][128 pairs] float2 ----------------------
__global__ void rope_tab_k(float2* __restrict__ tab) {
  int idx = blockIdx.x * 256 + threadIdx.x;      // 2048*256 = 524288 exactly
  int pos = idx >> 7, p = idx & 127;
  int t = (p < 64) ? (pos & 63) : (pos >> 6);    // axial: x then y
  int fr = p & 63;
  float freq = __expf(-(float)fr * (9.210340371976184f / 64.0f)); // 10000^-(fr/64)
  float ang = (float)t * freq;
  tab[idx] = make_float2(cosf(ang), sinf(ang));
}

// ---- mask dtype detection (bool u8 / int32 / float32) ----------------------
__global__ void mask_detect_k(const unsigned int* __restrict__ m, int* __restrict__ flag) {
  __shared__ int sI, sF;
  int t = threadIdx.x;
  if (t == 0) { sI = 1; sF = 1; }
  __syncthreads();
  int okI = 1, okF = 1;
  for (int i = t; i < 8224; i += 256) {          // 8224 words safe in all formats
    unsigned int w = m[i];
    if (w > 1u) okI = 0;
    if (w != 0u && w != 0x3F800000u) okF = 0;
  }
  if (!okI) atomicAnd(&sI, 0);
  if (!okF) atomicAnd(&sF, 0);
  __syncthreads();
  if (t == 0) flag[0] = sI ? 0 : (sF ? 1 : 2);   // 0=int32, 1=float32, 2=u8
}

__global__ void mask_conv_k(const void* __restrict__ src, const int* __restrict__ flag,
                            unsigned char* __restrict__ dst) {
  int i = blockIdx.x * 256 + threadIdx.x;
  if (i >= 2 * 16448) return;
  int f = flag[0];
  unsigned char v;
  if (f == 0)      v = ((const int*)src)[i] != 0;
  else if (f == 1) v = ((const float*)src)[i] != 0.0f;
  else             v = ((const unsigned char*)src)[i] != 0;
  dst[i] = v;
}

// ---- Q projection + rope -> bf16 qh[8192][256] -----------------------------
__global__ __launch_bounds__(256) void qproj_k(
    const float* __restrict__ q, const float* __restrict__ wq,
    const float* __restrict__ bq, const float2* __restrict__ tab,
    unsigned short* __restrict__ qh) {
  const int c = threadIdx.x;                 // output column
  const int rb = blockIdx.x * 8;             // 8-row strip
  float acc[8];
  const float bias = bq[c];
#pragma unroll
  for (int r = 0; r < 8; ++r) acc[r] = bias;
  for (int ch = 0; ch < 4; ++ch) {           // K=256 in 4 chunks of 64
    float wreg[64];
#pragma unroll
    for (int j = 0; j < 64; ++j) wreg[j] = wq[(ch * 64 + j) * 256 + c];
#pragma unroll
    for (int r = 0; r < 8; ++r) {
      const float* qr = q + (size_t)(rb + r) * 256 + ch * 64;  // uniform -> s_load
      float a = acc[r];
#pragma unroll
      for (int j = 0; j < 64; ++j) a += qr[j] * wreg[j];
      acc[r] = a;
    }
  }
  const int p = c >> 1;
#pragma unroll
  for (int r = 0; r < 8; ++r) {
    int pos = (rb + r) & 4095;
    float2 cs = tab[pos * 128 + p];
    float v = acc[r];
    float o = __shfl_xor(v, 1);              // pair partner (c ^ 1)
    float res = v * cs.x + ((c & 1) ? o * cs.y : -o * cs.y);
    qh[(size_t)(rb + r) * 256 + c] = f2bf(res);
  }
}

// ---- K/V projection: K -> rope + swizzled kh; V -> transposed+swizzled vt --
__global__ __launch_bounds__(256) void kvproj_k(
    const float* __restrict__ kin, const float* __restrict__ vin,
    const float* __restrict__ wk, const float* __restrict__ bk,
    const float* __restrict__ wv, const float* __restrict__ bv,
    const float2* __restrict__ tab, const int* __restrict__ nker,
    unsigned short* __restrict__ kh, unsigned short* __restrict__ vt) {
  __shared__ unsigned short vlds[64 * 262];  // 262 stride: odd dword count -> no conflicts
  const int c = threadIdx.x;                 // output column (d)
  const int kb = blockIdx.x;                 // key tile 0..256
  const int b = blockIdx.y;
  const int kind = blockIdx.z;               // 0 = K, 1 = V
  const float* in = (kind ? vin : kin) + ((size_t)b * 16448 + kb * 64) * 64;
  const float* wm = kind ? wv : wk;
  const float bias = (kind ? bv : bk)[c];
  float wreg[64];
#pragma unroll
  for (int j = 0; j < 64; ++j) wreg[j] = wm[j * 256 + c];
  const int nrope = 16448 - nker[0];
  for (int r = 0; r < 64; ++r) {
    const float* row = in + r * 64;          // uniform -> s_load
    float a = bias;
#pragma unroll
    for (int j = 0; j < 64; ++j) a += row[j] * wreg[j];
    if (kind == 0) {
      int grow = kb * 64 + r;
      if (grow < nrope) {                    // uniform branch
        float2 cs = tab[(grow & 4095) * 128 + (c >> 1)];
        float o = __shfl_xor(a, 1);
        a = a * cs.x + ((c & 1) ? o * cs.y : -o * cs.y);
      }
      // pre-swizzled row-major store: byte-in-row ^ ((row&7)<<4)
      size_t base = ((size_t)b * 16448 + (size_t)kb * 64 + r) * 512;
      *(unsigned short*)((char*)kh + base + ((2 * c) ^ ((r & 7) << 4))) = f2bf(a);
    } else {
      vlds[r * 262 + c] = f2bf(a);
    }
  }
  if (kind == 1) {
    __syncthreads();
    const int key = c & 63, w4 = c >> 6;
    char* tbase = (char*)vt + ((size_t)b * 257 + kb) * 32768;  // [256 d][64 key] tile
    for (int i = 0; i < 64; ++i) {
      int cc = w4 + i * 4;                   // d row
      unsigned short val = vlds[key * 262 + cc];
      *(unsigned short*)(tbase + cc * 128 + ((2 * key) ^ ((cc & 7) << 4))) = val;
    }
  }
}

// ---- flash attention, KV-split partials ------------------------------------
// grid (64 qblocks, nseg, 2 batches), 256 threads = 4 waves x 16 q rows.
// LDS: [0,32K) K tile (64 key x 512B swz), [32K,64K) V^T tile (256 d x 128B swz).
// P (per wave 2KB) aliases the K region behind a third barrier.
__global__ __launch_bounds__(256, 2) void attn_k(
    const unsigned short* __restrict__ qh, const unsigned short* __restrict__ kh,
    const unsigned short* __restrict__ vt, const unsigned char* __restrict__ maskc,
    float* __restrict__ part) {
  __shared__ __align__(16) char lds[65536];
  const int tid = threadIdx.x;
  const int w = tid >> 6, ln = tid & 63;
  const int lr = ln & 15, lg = ln >> 4;
  const int qb = blockIdx.x;
  const int seg = blockIdx.y, nseg = gridDim.y;
  const int b = blockIdx.z;

  // Q fragments: lane holds Q[row=lr][k=lg*8+j] per 32-wide k-chunk
  short8 qf[8];
  {
    const unsigned short* qrow = qh + ((size_t)(b * 4096 + qb * 64 + w * 16 + lr)) * 256;
#pragma unroll
    for (int kc = 0; kc < 8; ++kc)
      qf[kc] = *(const short8*)(qrow + kc * 32 + lg * 8);
  }
  const f4 fzero = {0.f, 0.f, 0.f, 0.f};
  f4 acc[16];                                 // out^T[d=dt*16+lg*4+j][q=lr]
#pragma unroll
  for (int i = 0; i < 16; ++i) acc[i] = fzero;
  float m_[4] = {-1e30f, -1e30f, -1e30f, -1e30f};
  float l_[4] = {0.f, 0.f, 0.f, 0.f};

  const int base = 257 / nseg, rem = 257 % nseg;
  const int it0 = seg * base + (seg < rem ? seg : rem);
  const int cnt = base + (seg < rem ? 1 : 0);

  const char* khb = (const char*)kh + (size_t)b * 16448 * 512;
  const char* vtb = (const char*)vt + (size_t)b * 257 * 32768;
  const unsigned char* mkb = maskc + (size_t)b * 16448;
  char* pb = lds + w * 2048;                  // per-wave P tile [16 q][128B swz]

  for (int ii = 0; ii < cnt; ++ii) {
    const int it = it0 + ii;
    __syncthreads();                          // prev iter done with LDS
    {
      const char* gK = khb + (size_t)it * 32768;
      const char* gV = vtb + (size_t)it * 32768;
#pragma unroll
      for (int r = 0; r < 8; ++r) {
        gl_lds16(gK + r * 4096 + w * 1024 + ln * 16, lds + r * 4096 + w * 1024);
        gl_lds16(gV + r * 4096 + w * 1024 + ln * 16, lds + 32768 + r * 4096 + w * 1024);
      }
    }
    __syncthreads();                          // barrier drains vmcnt -> tiles ready
    // ---- S = Q K^T : lane holds S[q=lg*4+j][key=nt*16+lr] ----
    f4 s[4];
#pragma unroll
    for (int nt = 0; nt < 4; ++nt) s[nt] = fzero;
#pragma unroll
    for (int kc = 0; kc < 8; ++kc) {
#pragma unroll
      for (int nt = 0; nt < 4; ++nt) {
        const int rr = nt * 16 + lr;          // key row in K tile
        const int off = rr * 512 + ((kc * 64 + lg * 16) ^ ((rr & 7) << 4));
        short8 kf = *(const short8*)(lds + off);
        s[nt] = __builtin_amdgcn_mfma_f32_16x16x32_bf16(qf[kc], kf, s[nt], 0, 0, 0);
      }
    }
    // ---- scale + mask + online softmax ----
#pragma unroll
    for (int nt = 0; nt < 4; ++nt) {
      float mb = mkb[it * 64 + nt * 16 + lr] ? 0.f : -30000.f;
#pragma unroll
      for (int j = 0; j < 4; ++j) s[nt][j] = s[nt][j] * 0.0625f + mb;
    }
    float tm[4];
#pragma unroll
    for (int j = 0; j < 4; ++j)
      tm[j] = fmaxf(fmaxf(s[0][j], s[1][j]), fmaxf(s[2][j], s[3][j]));
#pragma unroll
    for (int msk = 1; msk < 16; msk <<= 1) {
#pragma unroll
      for (int j = 0; j < 4; ++j) tm[j] = fmaxf(tm[j], __shfl_xor(tm[j], msk));
    }
    float scl[4], p[4][4], ts[4];
#pragma unroll
    for (int j = 0; j < 4; ++j) {
      float mn = fmaxf(m_[j], tm[j]);
      scl[j] = __expf(m_[j] - mn);
      m_[j] = mn;
    }
#pragma unroll
    for (int nt = 0; nt < 4; ++nt)
#pragma unroll
      for (int j = 0; j < 4; ++j) p[nt][j] = __expf(s[nt][j] - m_[j]);
#pragma unroll
    for (int j = 0; j < 4; ++j) ts[j] = (p[0][j] + p[1][j]) + (p[2][j] + p[3][j]);
#pragma unroll
    for (int msk = 1; msk < 16; msk <<= 1) {
#pragma unroll
      for (int j = 0; j < 4; ++j) ts[j] += __shfl_xor(ts[j], msk);
    }
#pragma unroll
    for (int j = 0; j < 4; ++j) l_[j] = l_[j] * scl[j] + ts[j];
    // rescale acc: factor lives at row q in stats lanes; acc column q = lr
    {
      const int src = (lr >> 2) << 4;
      float s0 = __shfl(scl[0], src), s1 = __shfl(scl[1], src);
      float s2 = __shfl(scl[2], src), s3 = __shfl(scl[3], src);
      const int e = lr & 3;
      float cs = (e == 0) ? s0 : (e == 1) ? s1 : (e == 2) ? s2 : s3;
#pragma unroll
      for (int dt = 0; dt < 16; ++dt)
#pragma unroll
        for (int j = 0; j < 4; ++j) acc[dt][j] *= cs;
    }
    __syncthreads();                          // all waves done reading K (P aliases it)
    // ---- P -> LDS bf16 (swizzled [16 q][64 key]) ----
#pragma unroll
    for (int nt = 0; nt < 4; ++nt)
#pragma unroll
      for (int j = 0; j < 4; ++j) {
        const int qq = lg * 4 + j, key = nt * 16 + lr;
        *(unsigned short*)(pb + qq * 128 + ((key * 2) ^ ((qq & 7) << 4))) = f2bf(p[nt][j]);
      }
    // ---- acc^T += V^T P^T ----
#pragma unroll
    for (int kc2 = 0; kc2 < 2; ++kc2) {
      short8 pf = *(const short8*)(pb + lr * 128 + ((kc2 * 64 + lg * 16) ^ ((lr & 7) << 4)));
#pragma unroll
      for (int dt = 0; dt < 16; ++dt) {
        const int rr = dt * 16 + lr;          // d row in V^T tile
        const int off = 32768 + rr * 128 + ((kc2 * 64 + lg * 16) ^ ((rr & 7) << 4));
        short8 vf = *(const short8*)(lds + off);
        acc[dt] = __builtin_amdgcn_mfma_f32_16x16x32_bf16(vf, pf, acc[dt], 0, 0, 0);
      }
    }
  }
  // ---- store partials: [seg][b][4096 q][260] (256 acc, m, l, pad) ----
  float* pp = part + ((size_t)((seg * 2 + b) * 4096 + qb * 64 + w * 16 + lr)) * 260;
#pragma unroll
  for (int dt = 0; dt < 16; ++dt)
    *(f4*)(pp + dt * 16 + lg * 4) = acc[dt];
  if (lr == 0) {
    float* ps = part + ((size_t)((seg * 2 + b) * 4096 + qb * 64 + w * 16)) * 260;
#pragma unroll
    for (int j = 0; j < 4; ++j) {
      ps[(lg * 4 + j) * 260 + 256] = m_[j];
      ps[(lg * 4 + j) * 260 + 257] = l_[j];
    }
  }
}

// ---- split-K combine -------------------------------------------------------
__global__ void combine_k(const float* __restrict__ part, int nseg,
                          float* __restrict__ attn) {
  const int row = blockIdx.x;                 // 0..8191
  const int b = row >> 12, rl = row & 4095;
  const int d = threadIdx.x;
  float m[4] = {-1e30f, -1e30f, -1e30f, -1e30f};
  float l[4] = {0.f, 0.f, 0.f, 0.f};
  float a[4] = {0.f, 0.f, 0.f, 0.f};
  float M = -1e30f;
#pragma unroll
  for (int s = 0; s < 4; ++s)
    if (s < nseg) {
      size_t ix = ((size_t)((s * 2 + b) * 4096 + rl)) * 260;
      m[s] = part[ix + 256];
      l[s] = part[ix + 257];
      a[s] = part[ix + d];
      M = fmaxf(M, m[s]);
    }
  float L = 0.f, val = 0.f;
#pragma unroll
  for (int s = 0; s < 4; ++s)
    if (s < nseg) {
      float wf = __expf(m[s] - M);
      L += l[s] * wf;
      val += a[s] * wf;
    }
  attn[(size_t)row * 256 + d] = val / L;
}

// ---- output GEMM: attn[8192,256] @ wo[256,256] + bo -> d_out ---------------
__global__ __launch_bounds__(256) void ogemm_k(
    const float* __restrict__ in, const float* __restrict__ wo,
    const float* __restrict__ bo, float* __restrict__ out) {
  const int c = threadIdx.x;
  const int rb = blockIdx.x * 8;
  float acc[8];
  const float bias = bo[c];
#pragma unroll
  for (int r = 0; r < 8; ++r) acc[r] = bias;
  for (int ch = 0; ch < 4; ++ch) {
    float wreg[64];
#pragma unroll
    for (int j = 0; j < 64; ++j) wreg[j] = wo[(ch * 64 + j) * 256 + c];
#pragma unroll
    for (int r = 0; r < 8; ++r) {
      const float* ir = in + (size_t)(rb + r) * 256 + ch * 64;
      float a = acc[r];
#pragma unroll
      for (int j = 0; j < 64; ++j) a += ir[j] * wreg[j];
      acc[r] = a;
    }
  }
#pragma unroll
  for (int r = 0; r < 8; ++r) out[(size_t)(rb + r) * 256 + c] = acc[r];
}

// ---------------------------------------------------------------------------
extern "C" void kernel_launch(void* const* d_in, const int* in_sizes, int n_in,
                              void* d_out, int out_size, void* d_ws, size_t ws_size,
                              hipStream_t stream) {
  const float* q  = (const float*)d_in[0];
  const float* k  = (const float*)d_in[1];
  const float* v  = (const float*)d_in[2];
  const void*  mk = d_in[3];
  const float* wq = (const float*)d_in[4];
  const float* bq = (const float*)d_in[5];
  const float* wk = (const float*)d_in[6];
  const float* bk = (const float*)d_in[7];
  const float* wv = (const float*)d_in[8];
  const float* bv = (const float*)d_in[9];
  const float* wo = (const float*)d_in[10];
  const float* bo = (const float*)d_in[11];
  const int* nker = (const int*)d_in[12];
  (void)in_sizes; (void)n_in; (void)out_size;

  char* ws = (char*)d_ws;
  size_t off = 0;
  auto alloc = [&](size_t sz) { size_t o = off; off = (off + sz + 255) & ~(size_t)255; return o; };
  const size_t o_tab  = alloc((size_t)4096 * 128 * 8);     // rope table
  const size_t o_qh   = alloc((size_t)8192 * 256 * 2);     // bf16 Q
  const size_t o_kh   = alloc((size_t)2 * 16448 * 256 * 2);// bf16 K (swizzled)
  const size_t o_vt   = alloc((size_t)2 * 257 * 32768);    // bf16 V^T tiles (swizzled)
  const size_t o_msk  = alloc(2 * 16448);                  // u8 mask
  const size_t o_flag = alloc(256);
  const size_t o_attn = alloc((size_t)8192 * 256 * 4);     // combined attn out (fp32)
  const size_t o_part = off;                               // split-K partials
  auto partsz = [](int s) { return (size_t)s * 2 * 4096 * 260 * 4; };
  int nseg = 4;
  while (nseg > 1 && o_part + partsz(nseg) > ws_size) nseg >>= 1;

  float2* tab        = (float2*)(ws + o_tab);
  unsigned short* qh = (unsigned short*)(ws + o_qh);
  unsigned short* kh = (unsigned short*)(ws + o_kh);
  unsigned short* vt = (unsigned short*)(ws + o_vt);
  unsigned char* mc  = (unsigned char*)(ws + o_msk);
  int* flag          = (int*)(ws + o_flag);
  float* attn        = (float*)(ws + o_attn);
  float* part        = (float*)(ws + o_part);

  rope_tab_k<<<dim3(2048), dim3(256), 0, stream>>>(tab);
  mask_detect_k<<<dim3(1), dim3(256), 0, stream>>>((const unsigned int*)mk, flag);
  mask_conv_k<<<dim3(129), dim3(256), 0, stream>>>(mk, flag, mc);
  qproj_k<<<dim3(1024), dim3(256), 0, stream>>>(q, wq, bq, tab, qh);
  kvproj_k<<<dim3(257, 2, 2), dim3(256), 0, stream>>>(k, v, wk, bk, wv, bv, tab, nker, kh, vt);
  attn_k<<<dim3(64, nseg, 2), dim3(256), 0, stream>>>(qh, kh, vt, mc, part);
  combine_k<<<dim3(8192), dim3(256), 0, stream>>>(part, nseg, attn);
  ogemm_k<<<dim3(1024), dim3(256), 0, stream>>>(attn, wo, bo, (float*)d_out);
}

// Round 2
// 426.085 us; speedup vs baseline: 1.2499x; 1.2499x over previous
//
#include <hip/hip_runtime.h>
#include <hip/hip_bf16.h>
#include <stdint.h>

// ---------------------------------------------------------------------------
// RoPE attention (B=2, SQ=4096, SK=16448, H=1, D=256) for MI355X (gfx950).
// r2: mask-compacted keys, swapped-QK in-register P (zero-shuffle via
// permuted K LDS rows), KVBLK=32 / 32KB LDS / 4 blocks/CU, defer-max,
// precomputed swizzled LDS bases, small rope table.
// ---------------------------------------------------------------------------

typedef __attribute__((ext_vector_type(8))) short short8;   // 8 x bf16 bits
typedef __attribute__((ext_vector_type(4))) float f4;       // MFMA C/D frag

__device__ __forceinline__ unsigned short f2bf(float x) {
  union { float f; uint32_t u; } v; v.f = x;
  return (unsigned short)((v.u + 0x7FFFu + ((v.u >> 16) & 1u)) >> 16);  // RNE
}

__device__ __forceinline__ uint32_t cvtpk(float a, float b) {
  uint32_t r;
  asm("v_cvt_pk_bf16_f32 %0, %1, %2" : "=v"(r) : "v"(a), "v"(b));
  return r;  // lo16 = bf16(a), hi16 = bf16(b)
}

__device__ __forceinline__ void gl_lds16(const void* g, void* l) {
  __builtin_amdgcn_global_load_lds(
      (const __attribute__((address_space(1))) void*)g,
      (__attribute__((address_space(3))) void*)l, 16, 0, 0);
}

// ---- rope cos/sin table: [64 t][64 f] float2 (axial; x and y share it) -----
__global__ void rope_tab_k(float2* __restrict__ tab) {
  int idx = blockIdx.x * 256 + threadIdx.x;      // 4096
  int t = idx >> 6, f = idx & 63;
  float freq = __expf(-(float)f * (9.210340371976184f / 64.0f)); // 10000^-(f/64)
  float ang = (float)t * freq;
  tab[idx] = make_float2(cosf(ang), sinf(ang));
}

// ---- mask dtype detection (int32 / float32 / u8) ---------------------------
__global__ void mask_detect_k(const unsigned int* __restrict__ m, int* __restrict__ flag) {
  __shared__ int sI, sF;
  int t = threadIdx.x;
  if (t == 0) { sI = 1; sF = 1; }
  __syncthreads();
  int okI = 1, okF = 1;
  for (int i = t; i < 2048; i += 256) {          // 8KB safe in all formats
    unsigned int w = m[i];
    if (w > 1u) okI = 0;
    if (w != 0u && w != 0x3F800000u) okF = 0;
  }
  if (!okI) atomicAnd(&sI, 0);
  if (!okF) atomicAnd(&sF, 0);
  __syncthreads();
  if (t == 0) flag[0] = sI ? 0 : (sF ? 1 : 2);   // 0=int32, 1=float32, 2=u8
}

__device__ __forceinline__ int mask_at(const void* mk, int f, int i) {
  if (f == 0) return ((const int*)mk)[i] != 0;
  if (f == 1) return ((const float*)mk)[i] != 0.0f;
  return ((const unsigned char*)mk)[i] != 0;
}

// ---- per-batch mask compaction: comp[ci] = orig key idx, ncomp[b] ----------
__global__ void scan_k(const void* __restrict__ mk, const int* __restrict__ flag,
                       int* __restrict__ comp, int* __restrict__ ncomp) {
  __shared__ int sc[256];
  const int b = blockIdx.x, t = threadIdx.x, f = flag[0];
  const int base = b * 16448;
  const int c0 = t * 65, c1 = min(c0 + 65, 16448);
  int c = 0;
  for (int i = c0; i < c1; ++i) c += mask_at(mk, f, base + i);
  sc[t] = c;
  __syncthreads();
  for (int off = 1; off < 256; off <<= 1) {      // Hillis-Steele inclusive
    int v = (t >= off) ? sc[t - off] : 0;
    __syncthreads();
    sc[t] += v;
    __syncthreads();
  }
  int w = sc[t] - c;                             // exclusive prefix
  int* cb = comp + base;
  for (int i = c0; i < c1; ++i)
    if (mask_at(mk, f, base + i)) cb[w++] = i;
  if (t == 255) ncomp[b] = sc[255];
}

// ---- Q projection + rope + 1/16 scale -> bf16 qh[8192][256] ----------------
__global__ __launch_bounds__(256) void qproj_k(
    const float* __restrict__ q, const float* __restrict__ wq,
    const float* __restrict__ bq, const float2* __restrict__ tab,
    unsigned short* __restrict__ qh) {
  const int c = threadIdx.x;
  const int rb = blockIdx.x * 8;
  float acc[8];
  const float bias = bq[c];
#pragma unroll
  for (int r = 0; r < 8; ++r) acc[r] = bias;
  for (int ch = 0; ch < 4; ++ch) {
    float wreg[64];
#pragma unroll
    for (int j = 0; j < 64; ++j) wreg[j] = wq[(ch * 64 + j) * 256 + c];
#pragma unroll
    for (int r = 0; r < 8; ++r) {
      const float* qr = q + (size_t)(rb + r) * 256 + ch * 64;  // uniform -> s_load
      float a = acc[r];
#pragma unroll
      for (int j = 0; j < 64; ++j) a += qr[j] * wreg[j];
      acc[r] = a;
    }
  }
  const int p = c >> 1;
#pragma unroll
  for (int r = 0; r < 8; ++r) {
    int pos = (rb + r) & 4095;
    float2 cs = (p < 64) ? tab[(pos & 63) * 64 + p] : tab[(pos >> 6) * 64 + (p - 64)];
    float v = acc[r];
    float o = __shfl_xor(v, 1);
    float res = v * cs.x + ((c & 1) ? o * cs.y : -o * cs.y);
    qh[(size_t)(rb + r) * 256 + c] = f2bf(res * 0.0625f);   // fold softmax scale
  }
}

// ---- K/V projection on COMPACTED keys --------------------------------------
// K: rope + permuted-row ( r(k)=((k>>2)&1)*16+(k>>3)*4+(k&3) ) + XOR-swizzled
//    rows of 512B -> kh[b][row][256] bf16.
// V: transposed tiles vt[b][tile][256 d][32 key] bf16, rows 64B (bank-balanced
//    unswizzled), written coalesced (thread = d-row).
__global__ __launch_bounds__(256) void kvproj_k(
    const float* __restrict__ kin, const float* __restrict__ vin,
    const float* __restrict__ wk, const float* __restrict__ bk,
    const float* __restrict__ wv, const float* __restrict__ bv,
    const float2* __restrict__ tab, const int* __restrict__ nker,
    const int* __restrict__ comp, const int* __restrict__ ncomp,
    unsigned short* __restrict__ kh, unsigned short* __restrict__ vt) {
  __shared__ unsigned short vlds[64 * 258];
  const int c = threadIdx.x;
  const int kb = blockIdx.x, b = blockIdx.y, kind = blockIdx.z;
  const int nc = ncomp[b];
  const int pad = (nc + 31) & ~31;
  if (kb * 64 >= pad) return;
  const float* wm = kind ? wv : wk;
  const float bias = (kind ? bv : bk)[c];
  float wreg[64];
#pragma unroll
  for (int j = 0; j < 64; ++j) wreg[j] = wm[j * 256 + c];
  const int nrope = 16448 - nker[0];
  const int* cmp = comp + b * 16448;
  const float* inb = (kind ? vin : kin) + (size_t)b * 16448 * 64;
  const int rmax = min(64, pad - kb * 64);
  for (int r = 0; r < rmax; ++r) {
    const int ci = kb * 64 + r;
    float a = 0.f;
    int oldrow = 0;
    if (ci < nc) {                               // uniform branch
      oldrow = cmp[ci];
      const float* row = inb + (size_t)oldrow * 64;   // uniform -> s_load
      a = bias;
#pragma unroll
      for (int j = 0; j < 64; ++j) a += row[j] * wreg[j];
    }
    if (kind == 0) {
      if (ci < nc && oldrow < nrope) {
        const int pos = oldrow & 4095, p = c >> 1;
        const float2 cs = (p < 64) ? tab[(pos & 63) * 64 + p]
                                   : tab[(pos >> 6) * 64 + (p - 64)];
        const float o = __shfl_xor(a, 1);
        a = a * cs.x + ((c & 1) ? o * cs.y : -o * cs.y);
      }
      const int kk = ci & 31;
      const int rr = ((kk >> 2) & 1) * 16 + (kk >> 3) * 4 + (kk & 3);
      const size_t rowg = (size_t)(ci & ~31) + rr;
      *(unsigned short*)((char*)kh + ((size_t)b * 16448 + rowg) * 512 +
                         ((2 * c) ^ ((rr & 7) << 4))) = f2bf(a);
    } else {
      vlds[r * 258 + c] = f2bf(a);
    }
  }
  if (kind == 1) {
    __syncthreads();
    char* tb = (char*)vt + ((size_t)b * 514 + (size_t)kb * 2) * 16384;
#pragma unroll
    for (int ti = 0; ti < 2; ++ti) {
      union { uint32_t w[16]; uint4 v4[4]; } u;
#pragma unroll
      for (int kk = 0; kk < 32; kk += 2) {
        uint32_t lo = vlds[(ti * 32 + kk) * 258 + c];
        uint32_t hi = vlds[(ti * 32 + kk + 1) * 258 + c];
        u.w[kk >> 1] = lo | (hi << 16);
      }
#pragma unroll
      for (int qd = 0; qd < 4; ++qd)
        *(uint4*)(tb + (size_t)ti * 16384 + c * 64 + qd * 16) = u.v4[qd];
    }
  }
}

// ---- flash attention over compacted keys, KV-split partials ----------------
// grid (nseg*2 segb, 64 qb), 256 thr = 4 waves x 16 q rows. LDS 32KB:
// [0,16K) K tile (32 key x 512B, permuted+swizzled), [16K,32K) V^T (256d x 64B).
// Swapped QK: lane holds P[q=lr][key lg*8+nt*4+j] -> PV B-frag is lane-local.
__global__ __launch_bounds__(256, 3) void attn_k(
    const unsigned short* __restrict__ qh, const unsigned short* __restrict__ kh,
    const unsigned short* __restrict__ vt, const int* __restrict__ ncomp,
    float* __restrict__ part, int nseg) {
  __shared__ __align__(16) char lds[32768];
  const int tid = threadIdx.x;
  const int w = tid >> 6, ln = tid & 63;
  const int lr = ln & 15, lg = ln >> 4;
  const int segb = blockIdx.x;                 // seg*2 + b  (XCD = segb%8)
  const int qb = blockIdx.y;
  const int seg = segb >> 1, b = segb & 1;
  const int nc = ncomp[b];
  const int ntiles = (nc + 31) >> 5;
  const int t0 = seg * ntiles / nseg;
  const int t1 = (seg + 1) * ntiles / nseg;

  short8 qf[8];
  {
    const unsigned short* qrow = qh + (size_t)(b * 4096 + qb * 64 + w * 16 + lr) * 256;
#pragma unroll
    for (int kc = 0; kc < 8; ++kc) qf[kc] = *(const short8*)(qrow + kc * 32 + lg * 8);
  }
  const f4 fz = {0.f, 0.f, 0.f, 0.f};
  f4 acc[16];
#pragma unroll
  for (int i = 0; i < 16; ++i) acc[i] = fz;
  float m_ = -1e30f, l_ = 0.f;

  // precomputed per-lane LDS bases (XOR swizzle folded; ds offsets immediate)
  const int S = (lr & 7) << 4;
  const int s6 = S & 64, Lo = (lg * 16) ^ (S & 48);
  const int baseE = lr * 512 + Lo + s6;        // even kc
  const int baseO = lr * 512 + Lo + (64 - s6); // odd kc
  const int baseV = 16384 + lr * 64 + lg * 16;

  const char* srcK = (const char*)kh + (size_t)b * 16448 * 512 + (size_t)t0 * 16384;
  const char* srcV = (const char*)vt + (size_t)b * 514 * 16384 + (size_t)t0 * 16384;
  const int stoff = tid * 16;

  for (int it = t0; it < t1; ++it) {
    __syncthreads();                           // prev iter done with LDS
#pragma unroll
    for (int r = 0; r < 4; ++r) {
      gl_lds16(srcK + r * 4096 + stoff, lds + r * 4096 + stoff);
      gl_lds16(srcV + r * 4096 + stoff, lds + 16384 + r * 4096 + stoff);
    }
    srcK += 16384; srcV += 16384;
    __syncthreads();                           // barrier drains vmcnt
    // ---- S^T = K Q^T : lane holds S[q=lr][key = lg*8 + nt*4 + j] ----
    f4 s[2] = {fz, fz};
#pragma unroll
    for (int kc = 0; kc < 8; ++kc) {
      const int base = (kc & 1) ? baseO : baseE;
      short8 k0 = *(const short8*)(lds + base + (kc >> 1) * 128);
      short8 k1 = *(const short8*)(lds + base + (kc >> 1) * 128 + 8192);
      s[0] = __builtin_amdgcn_mfma_f32_16x16x32_bf16(k0, qf[kc], s[0], 0, 0, 0);
      s[1] = __builtin_amdgcn_mfma_f32_16x16x32_bf16(k1, qf[kc], s[1], 0, 0, 0);
    }
    // ---- tail bounds mask (uniform branch; only last tile) ----
    if (it * 32 + 32 > nc) {
#pragma unroll
      for (int nt = 0; nt < 2; ++nt)
#pragma unroll
        for (int j = 0; j < 4; ++j)
          if (it * 32 + lg * 8 + nt * 4 + j >= nc) s[nt][j] = -30000.f;
    }
    // ---- online softmax (per-lane row; reduce over 4 lg lanes) ----
    float tm = fmaxf(fmaxf(fmaxf(s[0][0], s[0][1]), fmaxf(s[0][2], s[0][3])),
                     fmaxf(fmaxf(s[1][0], s[1][1]), fmaxf(s[1][2], s[1][3])));
    tm = fmaxf(tm, __shfl_xor(tm, 16));
    tm = fmaxf(tm, __shfl_xor(tm, 32));
    if (!__all(tm <= m_ + 8.f)) {              // defer-max (T13)
      const float mn = fmaxf(m_, tm);
      const float scl = __expf(m_ - mn);
      m_ = mn; l_ *= scl;
#pragma unroll
      for (int dt = 0; dt < 16; ++dt)
#pragma unroll
        for (int j = 0; j < 4; ++j) acc[dt][j] *= scl;
    }
    float p[8];
    float ts = 0.f;
#pragma unroll
    for (int nt = 0; nt < 2; ++nt)
#pragma unroll
      for (int j = 0; j < 4; ++j) {
        float e = __expf(s[nt][j] - m_);
        p[nt * 4 + j] = e; ts += e;
      }
    ts += __shfl_xor(ts, 16);
    ts += __shfl_xor(ts, 32);
    l_ += ts;
    union { uint32_t u[4]; short8 v; } pk;
#pragma unroll
    for (int i = 0; i < 4; ++i) pk.u[i] = cvtpk(p[2 * i], p[2 * i + 1]);
    const short8 pf = pk.v;
    // ---- acc^T += V^T P^T (B-frag lane-local) ----
#pragma unroll
    for (int dt = 0; dt < 16; ++dt) {
      short8 vf = *(const short8*)(lds + baseV + dt * 1024);
      acc[dt] = __builtin_amdgcn_mfma_f32_16x16x32_bf16(vf, pf, acc[dt], 0, 0, 0);
    }
  }
  // ---- store partials [segb][4096 q][260] ----
  float* pp = part + (size_t)(segb * 4096 + qb * 64 + w * 16 + lr) * 260;
#pragma unroll
  for (int dt = 0; dt < 16; ++dt) *(f4*)(pp + dt * 16 + lg * 4) = acc[dt];
  if (lg == 0) { pp[256] = m_; pp[257] = l_; }
}

// ---- split-K combine -------------------------------------------------------
__global__ void combine_k(const float* __restrict__ part, int nseg,
                          float* __restrict__ attn) {
  const int row = blockIdx.x;                  // 0..8191
  const int b = row >> 12, rl = row & 4095;
  const int d = threadIdx.x;
  float M = -1e30f;
  for (int s = 0; s < nseg; ++s)
    M = fmaxf(M, part[(size_t)((s * 2 + b) * 4096 + rl) * 260 + 256]);
  float L = 0.f, val = 0.f;
  for (int s = 0; s < nseg; ++s) {
    size_t ix = (size_t)((s * 2 + b) * 4096 + rl) * 260;
    float wf = __expf(part[ix + 256] - M);
    L += part[ix + 257] * wf;
    val += part[ix + d] * wf;
  }
  attn[(size_t)row * 256 + d] = val / L;
}

// ---- output GEMM: attn[8192,256] @ wo[256,256] + bo -> d_out ---------------
__global__ __launch_bounds__(256) void ogemm_k(
    const float* __restrict__ in, const float* __restrict__ wo,
    const float* __restrict__ bo, float* __restrict__ out) {
  const int c = threadIdx.x;
  const int rb = blockIdx.x * 8;
  float acc[8];
  const float bias = bo[c];
#pragma unroll
  for (int r = 0; r < 8; ++r) acc[r] = bias;
  for (int ch = 0; ch < 4; ++ch) {
    float wreg[64];
#pragma unroll
    for (int j = 0; j < 64; ++j) wreg[j] = wo[(ch * 64 + j) * 256 + c];
#pragma unroll
    for (int r = 0; r < 8; ++r) {
      const float* ir = in + (size_t)(rb + r) * 256 + ch * 64;
      float a = acc[r];
#pragma unroll
      for (int j = 0; j < 64; ++j) a += ir[j] * wreg[j];
      acc[r] = a;
    }
  }
#pragma unroll
  for (int r = 0; r < 8; ++r) out[(size_t)(rb + r) * 256 + c] = acc[r];
}

// ---------------------------------------------------------------------------
extern "C" void kernel_launch(void* const* d_in, const int* in_sizes, int n_in,
                              void* d_out, int out_size, void* d_ws, size_t ws_size,
                              hipStream_t stream) {
  const float* q  = (const float*)d_in[0];
  const float* k  = (const float*)d_in[1];
  const float* v  = (const float*)d_in[2];
  const void*  mk = d_in[3];
  const float* wq = (const float*)d_in[4];
  const float* bq = (const float*)d_in[5];
  const float* wk = (const float*)d_in[6];
  const float* bk = (const float*)d_in[7];
  const float* wv = (const float*)d_in[8];
  const float* bv = (const float*)d_in[9];
  const float* wo = (const float*)d_in[10];
  const float* bo = (const float*)d_in[11];
  const int* nker = (const int*)d_in[12];
  (void)in_sizes; (void)n_in; (void)out_size;

  char* ws = (char*)d_ws;
  size_t off = 0;
  auto alloc = [&](size_t sz) { size_t o = off; off = (off + sz + 255) & ~(size_t)255; return o; };
  const size_t o_tab  = alloc((size_t)64 * 64 * 8);          // rope table 32KB
  const size_t o_qh   = alloc((size_t)8192 * 256 * 2);       // bf16 Q (pre-scaled)
  const size_t o_kh   = alloc((size_t)2 * 16448 * 512);      // bf16 K compact (swz)
  const size_t o_vt   = alloc((size_t)2 * 514 * 16384);      // bf16 V^T tiles
  const size_t o_cmp  = alloc((size_t)2 * 16448 * 4);        // compaction map
  const size_t o_ncmp = alloc(256);
  const size_t o_flag = alloc(256);
  const size_t o_attn = alloc((size_t)8192 * 256 * 4);       // combined attn (fp32)
  const size_t o_part = off;                                 // split-K partials
  auto partsz = [](int s) { return (size_t)s * 2 * 4096 * 260 * 4; };
  int nseg = 8;
  while (nseg > 1 && o_part + partsz(nseg) > ws_size) nseg >>= 1;

  float2* tab        = (float2*)(ws + o_tab);
  unsigned short* qh = (unsigned short*)(ws + o_qh);
  unsigned short* kh = (unsigned short*)(ws + o_kh);
  unsigned short* vt = (unsigned short*)(ws + o_vt);
  int* comp          = (int*)(ws + o_cmp);
  int* ncomp         = (int*)(ws + o_ncmp);
  int* flag          = (int*)(ws + o_flag);
  float* attn        = (float*)(ws + o_attn);
  float* part        = (float*)(ws + o_part);

  rope_tab_k<<<dim3(16), dim3(256), 0, stream>>>(tab);
  mask_detect_k<<<dim3(1), dim3(256), 0, stream>>>((const unsigned int*)mk, flag);
  scan_k<<<dim3(2), dim3(256), 0, stream>>>(mk, flag, comp, ncomp);
  qproj_k<<<dim3(1024), dim3(256), 0, stream>>>(q, wq, bq, tab, qh);
  kvproj_k<<<dim3(257, 2, 2), dim3(256), 0, stream>>>(k, v, wk, bk, wv, bv, tab, nker,
                                                      comp, ncomp, kh, vt);
  attn_k<<<dim3(nseg * 2, 64), dim3(256), 0, stream>>>(qh, kh, vt, ncomp, part, nseg);
  combine_k<<<dim3(8192), dim3(256), 0, stream>>>(part, nseg, attn);
  ogemm_k<<<dim3(1024), dim3(256), 0, stream>>>(attn, wo, bo, (float*)d_out);
}

// Round 4
// 391.067 us; speedup vs baseline: 1.3618x; 1.0895x over previous
//
#include <hip/hip_runtime.h>
#include <hip/hip_bf16.h>
#include <stdint.h>

// ---------------------------------------------------------------------------
// RoPE attention (B=2, SQ=4096, SK=16448, H=1, D=256) for MI355X (gfx950).
// r4: r2-proven two-barrier K staging (single 16KB buffer), QBLK=128
// (2 q-groups/wave), V direct-from-global in 4-reg batches, fused
// combine+ogemm. No inline-asm waitcnts; register peak kept < 256.
// ---------------------------------------------------------------------------

typedef __attribute__((ext_vector_type(8))) short short8;   // 8 x bf16 bits
typedef __attribute__((ext_vector_type(4))) float f4;       // MFMA C/D frag

__device__ __forceinline__ unsigned short f2bf(float x) {
  union { float f; uint32_t u; } v; v.f = x;
  return (unsigned short)((v.u + 0x7FFFu + ((v.u >> 16) & 1u)) >> 16);  // RNE
}

__device__ __forceinline__ uint32_t cvtpk(float a, float b) {
  uint32_t r;
  asm("v_cvt_pk_bf16_f32 %0, %1, %2" : "=v"(r) : "v"(a), "v"(b));
  return r;  // lo16 = bf16(a), hi16 = bf16(b)
}

__device__ __forceinline__ void gl_lds16(const void* g, void* l) {
  __builtin_amdgcn_global_load_lds(
      (const __attribute__((address_space(1))) void*)g,
      (__attribute__((address_space(3))) void*)l, 16, 0, 0);
}

// ---- rope cos/sin table: [64 t][64 f] float2 (axial; x and y share it) -----
__global__ void rope_tab_k(float2* __restrict__ tab) {
  int idx = blockIdx.x * 256 + threadIdx.x;      // 4096
  int t = idx >> 6, f = idx & 63;
  float freq = __expf(-(float)f * (9.210340371976184f / 64.0f)); // 10000^-(f/64)
  float ang = (float)t * freq;
  tab[idx] = make_float2(cosf(ang), sinf(ang));
}

// ---- mask dtype detection (int32 / float32 / u8) ---------------------------
__global__ void mask_detect_k(const unsigned int* __restrict__ m, int* __restrict__ flag) {
  __shared__ int sI, sF;
  int t = threadIdx.x;
  if (t == 0) { sI = 1; sF = 1; }
  __syncthreads();
  int okI = 1, okF = 1;
  for (int i = t; i < 2048; i += 256) {          // 8KB safe in all formats
    unsigned int w = m[i];
    if (w > 1u) okI = 0;
    if (w != 0u && w != 0x3F800000u) okF = 0;
  }
  if (!okI) atomicAnd(&sI, 0);
  if (!okF) atomicAnd(&sF, 0);
  __syncthreads();
  if (t == 0) flag[0] = sI ? 0 : (sF ? 1 : 2);   // 0=int32, 1=float32, 2=u8
}

__device__ __forceinline__ int mask_at(const void* mk, int f, int i) {
  if (f == 0) return ((const int*)mk)[i] != 0;
  if (f == 1) return ((const float*)mk)[i] != 0.0f;
  return ((const unsigned char*)mk)[i] != 0;
}

// ---- per-batch mask compaction: comp[ci] = orig key idx, ncomp[b] ----------
__global__ void scan_k(const void* __restrict__ mk, const int* __restrict__ flag,
                       int* __restrict__ comp, int* __restrict__ ncomp) {
  __shared__ int sc[256];
  const int b = blockIdx.x, t = threadIdx.x, f = flag[0];
  const int base = b * 16448;
  const int c0 = t * 65, c1 = min(c0 + 65, 16448);
  int c = 0;
  for (int i = c0; i < c1; ++i) c += mask_at(mk, f, base + i);
  sc[t] = c;
  __syncthreads();
  for (int off = 1; off < 256; off <<= 1) {      // Hillis-Steele inclusive
    int v = (t >= off) ? sc[t - off] : 0;
    __syncthreads();
    sc[t] += v;
    __syncthreads();
  }
  int w = sc[t] - c;                             // exclusive prefix
  int* cb = comp + base;
  for (int i = c0; i < c1; ++i)
    if (mask_at(mk, f, base + i)) cb[w++] = i;
  if (t == 255) ncomp[b] = sc[255];
}

// ---- Q projection + rope + 1/16 scale -> bf16 qh[8192][256] ----------------
__global__ __launch_bounds__(256) void qproj_k(
    const float* __restrict__ q, const float* __restrict__ wq,
    const float* __restrict__ bq, const float2* __restrict__ tab,
    unsigned short* __restrict__ qh) {
  const int c = threadIdx.x;
  const int rb = blockIdx.x * 8;
  float acc[8];
  const float bias = bq[c];
#pragma unroll
  for (int r = 0; r < 8; ++r) acc[r] = bias;
  for (int ch = 0; ch < 4; ++ch) {
    float wreg[64];
#pragma unroll
    for (int j = 0; j < 64; ++j) wreg[j] = wq[(ch * 64 + j) * 256 + c];
#pragma unroll
    for (int r = 0; r < 8; ++r) {
      const float* qr = q + (size_t)(rb + r) * 256 + ch * 64;  // uniform -> s_load
      float a = acc[r];
#pragma unroll
      for (int j = 0; j < 64; ++j) a += qr[j] * wreg[j];
      acc[r] = a;
    }
  }
  const int p = c >> 1;
#pragma unroll
  for (int r = 0; r < 8; ++r) {
    int pos = (rb + r) & 4095;
    float2 cs = (p < 64) ? tab[(pos & 63) * 64 + p] : tab[(pos >> 6) * 64 + (p - 64)];
    float v = acc[r];
    float o = __shfl_xor(v, 1);
    float res = v * cs.x + ((c & 1) ? o * cs.y : -o * cs.y);
    qh[(size_t)(rb + r) * 256 + c] = f2bf(res * 0.0625f);   // fold softmax scale
  }
}

// ---- K/V projection on COMPACTED keys --------------------------------------
// K: rope + permuted-row ( r(k)=((k>>2)&1)*16+(k>>3)*4+(k&3) ) + XOR-swizzled
//    rows of 512B -> kh[b][row][256] bf16.
// V: transposed tiles vt[b][tile][256 d][32 key] bf16 (64B rows, coalesced).
__global__ __launch_bounds__(256) void kvproj_k(
    const float* __restrict__ kin, const float* __restrict__ vin,
    const float* __restrict__ wk, const float* __restrict__ bk,
    const float* __restrict__ wv, const float* __restrict__ bv,
    const float2* __restrict__ tab, const int* __restrict__ nker,
    const int* __restrict__ comp, const int* __restrict__ ncomp,
    unsigned short* __restrict__ kh, unsigned short* __restrict__ vt) {
  __shared__ unsigned short vlds[64 * 258];
  const int c = threadIdx.x;
  const int kb = blockIdx.x, b = blockIdx.y, kind = blockIdx.z;
  const int nc = ncomp[b];
  const int pad = (nc + 31) & ~31;
  if (kb * 64 >= pad) return;
  const float* wm = kind ? wv : wk;
  const float bias = (kind ? bv : bk)[c];
  float wreg[64];
#pragma unroll
  for (int j = 0; j < 64; ++j) wreg[j] = wm[j * 256 + c];
  const int nrope = 16448 - nker[0];
  const int* cmp = comp + b * 16448;
  const float* inb = (kind ? vin : kin) + (size_t)b * 16448 * 64;
  const int rmax = min(64, pad - kb * 64);
  for (int r = 0; r < rmax; ++r) {
    const int ci = kb * 64 + r;
    float a = 0.f;
    int oldrow = 0;
    if (ci < nc) {                               // uniform branch
      oldrow = cmp[ci];
      const float* row = inb + (size_t)oldrow * 64;   // uniform -> s_load
      a = bias;
#pragma unroll
      for (int j = 0; j < 64; ++j) a += row[j] * wreg[j];
    }
    if (kind == 0) {
      if (ci < nc && oldrow < nrope) {
        const int pos = oldrow & 4095, p = c >> 1;
        const float2 cs = (p < 64) ? tab[(pos & 63) * 64 + p]
                                   : tab[(pos >> 6) * 64 + (p - 64)];
        const float o = __shfl_xor(a, 1);
        a = a * cs.x + ((c & 1) ? o * cs.y : -o * cs.y);
      }
      const int kk = ci & 31;
      const int rr = ((kk >> 2) & 1) * 16 + (kk >> 3) * 4 + (kk & 3);
      const size_t rowg = (size_t)(ci & ~31) + rr;
      *(unsigned short*)((char*)kh + ((size_t)b * 16448 + rowg) * 512 +
                         ((2 * c) ^ ((rr & 7) << 4))) = f2bf(a);
    } else {
      vlds[r * 258 + c] = f2bf(a);
    }
  }
  if (kind == 1) {
    __syncthreads();
    char* tb = (char*)vt + ((size_t)b * 514 + (size_t)kb * 2) * 16384;
#pragma unroll
    for (int ti = 0; ti < 2; ++ti) {
      union { uint32_t w[16]; uint4 v4[4]; } u;
#pragma unroll
      for (int kk = 0; kk < 32; kk += 2) {
        uint32_t lo = vlds[(ti * 32 + kk) * 258 + c];
        uint32_t hi = vlds[(ti * 32 + kk + 1) * 258 + c];
        u.w[kk >> 1] = lo | (hi << 16);
      }
#pragma unroll
      for (int qd = 0; qd < 4; ++qd)
        *(uint4*)(tb + (size_t)ti * 16384 + c * 64 + qd * 16) = u.v4[qd];
    }
  }
}

// ---- flash attention, KV-split partials ------------------------------------
// grid (nseg*2 segb, 32 qb), 256 thr = 4 waves x 32 q rows (2 groups of 16).
// LDS: single 16KB K tile (32 key x 512B, permuted+swizzled rows), r2-proven
// two-barrier staging. V^T read directly from global (L1/L2) in 4-reg batches.
__global__ __launch_bounds__(256, 2) void attn_k(
    const unsigned short* __restrict__ qh, const unsigned short* __restrict__ kh,
    const unsigned short* __restrict__ vt, const int* __restrict__ ncomp,
    float* __restrict__ part, int nseg) {
  __shared__ __align__(16) char lds[16384];
  const int tid = threadIdx.x;
  const int w = tid >> 6, ln = tid & 63;
  const int lr = ln & 15, lg = ln >> 4;
  const int segb = blockIdx.x;                 // seg*2+b (XCD = segb%8)
  const int qb = blockIdx.y;
  const int seg = segb >> 1, b = segb & 1;
  const int nc = ncomp[b];
  const int ntiles = (nc + 31) >> 5;
  const int t0 = seg * ntiles / nseg;
  const int t1 = (seg + 1) * ntiles / nseg;

  // Q fragments for 2 q-groups of 16 rows each
  short8 qf[2][8];
  {
    const unsigned short* qr = qh + (size_t)(b * 4096 + qb * 128 + w * 32 + lr) * 256;
#pragma unroll
    for (int g = 0; g < 2; ++g)
#pragma unroll
      for (int kc = 0; kc < 8; ++kc)
        qf[g][kc] = *(const short8*)(qr + g * 16 * 256 + kc * 32 + lg * 8);
  }
  const f4 fz = {0.f, 0.f, 0.f, 0.f};
  f4 acc[2][16];
#pragma unroll
  for (int g = 0; g < 2; ++g)
#pragma unroll
    for (int i = 0; i < 16; ++i) acc[g][i] = fz;
  float m_[2] = {-1e30f, -1e30f}, l_[2] = {0.f, 0.f};

  // per-lane swizzled K read bases
  const int S = (lr & 7) << 4;
  const int s6 = S & 64, Lo = (lg * 16) ^ (S & 48);
  const int baseE = lr * 512 + Lo + s6;        // even kc
  const int baseO = lr * 512 + Lo + (64 - s6); // odd kc

  const char* srcK = (const char*)kh + (size_t)b * 16448 * 512 + (size_t)t0 * 16384;
  const char* gV = (const char*)vt + (size_t)b * 514 * 16384 + (size_t)t0 * 16384
                   + lr * 64 + lg * 16;
  const int stoff = tid * 16;

  for (int it = t0; it < t1; ++it) {
    __syncthreads();                           // all waves done reading prev K
#pragma unroll
    for (int r = 0; r < 4; ++r)
      gl_lds16(srcK + r * 4096 + stoff, lds + r * 4096 + stoff);
    srcK += 16384;
    __syncthreads();                           // drains vmcnt -> K tile ready
    // ---- S^T = K Q^T : lane holds S[q=lr(grp)][key = lg*8 + nt*4 + j] ----
    f4 s[2][2] = {{fz, fz}, {fz, fz}};
#pragma unroll
    for (int kc = 0; kc < 8; ++kc) {
      const int off = ((kc & 1) ? baseO : baseE) + (kc >> 1) * 128;
      short8 k0 = *(const short8*)(lds + off);
      short8 k1 = *(const short8*)(lds + off + 8192);
      s[0][0] = __builtin_amdgcn_mfma_f32_16x16x32_bf16(k0, qf[0][kc], s[0][0], 0, 0, 0);
      s[1][0] = __builtin_amdgcn_mfma_f32_16x16x32_bf16(k0, qf[1][kc], s[1][0], 0, 0, 0);
      s[0][1] = __builtin_amdgcn_mfma_f32_16x16x32_bf16(k1, qf[0][kc], s[0][1], 0, 0, 0);
      s[1][1] = __builtin_amdgcn_mfma_f32_16x16x32_bf16(k1, qf[1][kc], s[1][1], 0, 0, 0);
    }
    // ---- tail bounds mask (uniform branch; only last tile) ----
    if (it * 32 + 32 > nc) {
#pragma unroll
      for (int nt = 0; nt < 2; ++nt)
#pragma unroll
        for (int j = 0; j < 4; ++j)
          if (it * 32 + lg * 8 + nt * 4 + j >= nc) {
            s[0][nt][j] = -30000.f; s[1][nt][j] = -30000.f;
          }
    }
    // ---- online softmax (per-lane rows; reduce over 4 lg lanes) ----
    float tm[2];
#pragma unroll
    for (int g = 0; g < 2; ++g) {
      float t = fmaxf(fmaxf(fmaxf(s[g][0][0], s[g][0][1]), fmaxf(s[g][0][2], s[g][0][3])),
                      fmaxf(fmaxf(s[g][1][0], s[g][1][1]), fmaxf(s[g][1][2], s[g][1][3])));
      t = fmaxf(t, __shfl_xor(t, 16));
      t = fmaxf(t, __shfl_xor(t, 32));
      tm[g] = t;
    }
    if (!__all(tm[0] <= m_[0] + 8.f && tm[1] <= m_[1] + 8.f)) {   // defer-max
#pragma unroll
      for (int g = 0; g < 2; ++g) {
        const float mn = fmaxf(m_[g], tm[g]);
        const float sc = __expf(m_[g] - mn);
        m_[g] = mn; l_[g] *= sc;
#pragma unroll
        for (int dt = 0; dt < 16; ++dt)
#pragma unroll
          for (int j = 0; j < 4; ++j) acc[g][dt][j] *= sc;
      }
    }
    short8 pf[2];
#pragma unroll
    for (int g = 0; g < 2; ++g) {
      union { uint32_t u[4]; short8 v; } pk;
      float ts = 0.f;
#pragma unroll
      for (int nt = 0; nt < 2; ++nt)
#pragma unroll
        for (int jj = 0; jj < 4; jj += 2) {
          float e0 = __expf(s[g][nt][jj] - m_[g]);
          float e1 = __expf(s[g][nt][jj + 1] - m_[g]);
          ts += e0 + e1;
          pk.u[nt * 2 + (jj >> 1)] = cvtpk(e0, e1);
        }
      ts += __shfl_xor(ts, 16);
      ts += __shfl_xor(ts, 32);
      l_[g] += ts;
      pf[g] = pk.v;
    }
    // ---- acc^T += V^T P^T : V frags direct from global, 4-reg batches ----
#pragma unroll
    for (int bt = 0; bt < 4; ++bt) {
      short8 vf[4];
#pragma unroll
      for (int i = 0; i < 4; ++i) vf[i] = *(const short8*)(gV + (bt * 4 + i) * 1024);
#pragma unroll
      for (int dt = 0; dt < 4; ++dt) {
        acc[0][bt * 4 + dt] = __builtin_amdgcn_mfma_f32_16x16x32_bf16(vf[dt], pf[0], acc[0][bt * 4 + dt], 0, 0, 0);
        acc[1][bt * 4 + dt] = __builtin_amdgcn_mfma_f32_16x16x32_bf16(vf[dt], pf[1], acc[1][bt * 4 + dt], 0, 0, 0);
      }
    }
    gV += 16384;
  }
  // ---- store partials [segb][4096 q][260] ----
  const int qrow = qb * 128 + w * 32 + lr;
#pragma unroll
  for (int g = 0; g < 2; ++g) {
    float* pp = part + ((size_t)segb * 4096 + qrow + g * 16) * 260;
#pragma unroll
    for (int dt = 0; dt < 16; ++dt) *(f4*)(pp + dt * 16 + lg * 4) = acc[g][dt];
    if (lg == 0) { pp[256] = m_[g]; pp[257] = l_[g]; }
  }
}

// ---- fused split-K combine + output GEMM -----------------------------------
__global__ __launch_bounds__(256) void cogemm_k(
    const float* __restrict__ part, int nseg, const float* __restrict__ wo,
    const float* __restrict__ bo, float* __restrict__ out) {
  __shared__ float rows[8][256];
  const int c = threadIdx.x;
  const int rb = blockIdx.x * 8;
  for (int r = 0; r < 8; ++r) {
    const int row = rb + r, b = row >> 12, rl = row & 4095;
    float M = -1e30f;
    for (int s = 0; s < nseg; ++s)
      M = fmaxf(M, part[(size_t)((s * 2 + b) * 4096 + rl) * 260 + 256]);
    float L = 0.f, val = 0.f;
    for (int s = 0; s < nseg; ++s) {
      size_t ix = (size_t)((s * 2 + b) * 4096 + rl) * 260;
      float wf = __expf(part[ix + 256] - M);
      L += part[ix + 257] * wf;
      val += part[ix + c] * wf;
    }
    rows[r][c] = val / L;
  }
  __syncthreads();
  float acc[8];
  const float bias = bo[c];
#pragma unroll
  for (int r = 0; r < 8; ++r) acc[r] = bias;
  for (int ch = 0; ch < 4; ++ch) {
    float wreg[64];
#pragma unroll
    for (int j = 0; j < 64; ++j) wreg[j] = wo[(ch * 64 + j) * 256 + c];
#pragma unroll
    for (int r = 0; r < 8; ++r) {
      const float* ir = &rows[r][ch * 64];     // LDS broadcast reads
      float a = acc[r];
#pragma unroll
      for (int j = 0; j < 64; ++j) a += ir[j] * wreg[j];
      acc[r] = a;
    }
  }
#pragma unroll
  for (int r = 0; r < 8; ++r) out[(size_t)(rb + r) * 256 + c] = acc[r];
}

// ---------------------------------------------------------------------------
extern "C" void kernel_launch(void* const* d_in, const int* in_sizes, int n_in,
                              void* d_out, int out_size, void* d_ws, size_t ws_size,
                              hipStream_t stream) {
  const float* q  = (const float*)d_in[0];
  const float* k  = (const float*)d_in[1];
  const float* v  = (const float*)d_in[2];
  const void*  mk = d_in[3];
  const float* wq = (const float*)d_in[4];
  const float* bq = (const float*)d_in[5];
  const float* wk = (const float*)d_in[6];
  const float* bk = (const float*)d_in[7];
  const float* wv = (const float*)d_in[8];
  const float* bv = (const float*)d_in[9];
  const float* wo = (const float*)d_in[10];
  const float* bo = (const float*)d_in[11];
  const int* nker = (const int*)d_in[12];
  (void)in_sizes; (void)n_in; (void)out_size;

  char* ws = (char*)d_ws;
  size_t off = 0;
  auto alloc = [&](size_t sz) { size_t o = off; off = (off + sz + 255) & ~(size_t)255; return o; };
  const size_t o_tab  = alloc((size_t)64 * 64 * 8);          // rope table 32KB
  const size_t o_qh   = alloc((size_t)8192 * 256 * 2);       // bf16 Q (pre-scaled)
  const size_t o_kh   = alloc((size_t)2 * 16448 * 512);      // bf16 K compact (swz)
  const size_t o_vt   = alloc((size_t)2 * 514 * 16384);      // bf16 V^T tiles
  const size_t o_cmp  = alloc((size_t)2 * 16448 * 4);        // compaction map
  const size_t o_ncmp = alloc(256);
  const size_t o_flag = alloc(256);
  const size_t o_part = off;                                 // split-K partials
  auto partsz = [](int s) { return (size_t)s * 2 * 4096 * 260 * 4; };
  int nseg = 8;
  while (nseg > 1 && o_part + partsz(nseg) > ws_size) nseg >>= 1;

  float2* tab        = (float2*)(ws + o_tab);
  unsigned short* qh = (unsigned short*)(ws + o_qh);
  unsigned short* kh = (unsigned short*)(ws + o_kh);
  unsigned short* vt = (unsigned short*)(ws + o_vt);
  int* comp          = (int*)(ws + o_cmp);
  int* ncomp         = (int*)(ws + o_ncmp);
  int* flag          = (int*)(ws + o_flag);
  float* part        = (float*)(ws + o_part);

  rope_tab_k<<<dim3(16), dim3(256), 0, stream>>>(tab);
  mask_detect_k<<<dim3(1), dim3(256), 0, stream>>>((const unsigned int*)mk, flag);
  scan_k<<<dim3(2), dim3(256), 0, stream>>>(mk, flag, comp, ncomp);
  qproj_k<<<dim3(1024), dim3(256), 0, stream>>>(q, wq, bq, tab, qh);
  kvproj_k<<<dim3(257, 2, 2), dim3(256), 0, stream>>>(k, v, wk, bk, wv, bv, tab, nker,
                                                      comp, ncomp, kh, vt);
  attn_k<<<dim3(nseg * 2, 32), dim3(256), 0, stream>>>(qh, kh, vt, ncomp, part, nseg);
  cogemm_k<<<dim3(1024), dim3(256), 0, stream>>>(part, nseg, wo, bo, (float*)d_out);
}